// Round 2
// baseline (1206.421 us; speedup 1.0000x reference)
//
#include <hip/hip_runtime.h>
#include <math.h>

#define NPT   8192
#define FIN   256
#define DD    64
#define KSEL  48
#define QT    32
#define CT    128

#define LEAKY(x) (((x) >= 0.f) ? (x) : 0.01f*(x))

// ---------------- K0: transpose Wl (256x192 -> 192x256) ----------------
__global__ void k0_transpose(const float* __restrict__ Wl, float* __restrict__ WlT) {
  int j = blockIdx.x;            // 0..191
  int o = threadIdx.x;           // 0..255
  WlT[j*256 + o] = Wl[o*192 + j];
}

// ---------------- K1: per-node precompute (fp64) ----------------
// f = feature@Wb.T + bb ; sq = ||f||^2 ; u = f@Wt.T ; c = f@Wp.T + bp + u + bt
__global__ __launch_bounds__(256) void k1_precompute(
    const float* __restrict__ feature, const float* __restrict__ Wb, const float* __restrict__ bb,
    const float* __restrict__ Wt1, const float* __restrict__ bt1,
    const float* __restrict__ Wp1, const float* __restrict__ bp1,
    const float* __restrict__ Wt2, const float* __restrict__ bt2,
    const float* __restrict__ Wp2, const float* __restrict__ bp2,
    double* __restrict__ f64d, double* __restrict__ sq64,
    float* __restrict__ f32v, float* __restrict__ sqf,
    float* __restrict__ u1, float* __restrict__ c1,
    float* __restrict__ u2, float* __restrict__ c2)
{
  const int w = threadIdx.x >> 6, l = threadIdx.x & 63;
  const int i = blockIdx.x*4 + w;
  const float* frow = feature + i*FIN;
  const float* wrow = Wb + l*FIN;
  double facc = (double)bb[l];
  #pragma unroll 8
  for (int j = 0; j < FIN; ++j) facc += (double)frow[j] * (double)wrow[j];
  f64d[i*DD + l] = facc;
  f32v[i*DD + l] = (float)facc;
  double s = facc*facc;
  #pragma unroll
  for (int off = 32; off; off >>= 1) s += __shfl_xor(s, off);
  if (l == 0) { sq64[i] = s; sqf[i] = (float)s; }
  double au1 = 0.0, ap1 = 0.0, au2 = 0.0, ap2 = 0.0;
  for (int e = 0; e < DD; ++e) {
    double fe = __shfl(facc, e);
    au1 += fe * (double)Wt1[l*DD + e];
    ap1 += fe * (double)Wp1[l*DD + e];
    au2 += fe * (double)Wt2[l*DD + e];
    ap2 += fe * (double)Wp2[l*DD + e];
  }
  u1[i*DD+l] = (float)au1;
  c1[i*DD+l] = (float)(ap1 + (double)bp1[l] + au1 + (double)bt1[l]);
  u2[i*DD+l] = (float)au2;
  c2[i*DD+l] = (float)(ap2 + (double)bp2[l] + au2 + (double)bt2[l]);
}

// ---------------- K2: streaming KNN top-48 (fp32) ----------------
// Block: 256 thr, QT=32 queries; candidates in chunks of CT=128.
// 4q x 4c register tile; lane tc owns candidates {tc, tc+32, tc+64, tc+96}
// so fc_s b128 reads hit the canonical conflict-free bank pattern and
// dist_s stores are lane-contiguous.
__global__ __launch_bounds__(256) void k2_knn(
    const float* __restrict__ f32v, const float* __restrict__ sqf,
    int* __restrict__ idx48)
{
  __shared__ __align__(16) float fq_s[QT*68];
  __shared__ __align__(16) float fc_s[CT*68];
  __shared__ float dist_s[QT*132];
  __shared__ float knn_d[QT*KSEL];
  __shared__ int   knn_i[QT*KSEL];
  __shared__ float sqq_s[QT];
  __shared__ float sqc_s[CT];

  const int t = threadIdx.x;
  const int qbase = blockIdx.x * QT;

  for (int r = t; r < QT*KSEL; r += 256) { knn_d[r] = __builtin_inff(); knn_i[r] = 0; }
  #pragma unroll
  for (int r = 0; r < 2; ++r) {
    int flat = t + 256*r;
    int q = flat >> 4, d4 = flat & 15;
    float4 g = *(const float4*)&f32v[(qbase+q)*DD + 4*d4];
    *(float4*)&fq_s[q*68 + 4*d4] = g;
  }
  if (t < QT) sqq_s[t] = sqf[qbase + t];

  const int qg = t >> 5;   // 0..7 -> q0 = 4*qg
  const int tc = t & 31;   // candidate lane
  const int q0 = 4*qg;
  const int w = t >> 6, l = t & 63;

  for (int cb = 0; cb < NPT/CT; ++cb) {
    const int jbase = cb * CT;
    __syncthreads();
    // stage candidate chunk
    #pragma unroll
    for (int r = 0; r < 8; ++r) {
      int flat = t + 256*r;
      int c = flat >> 4, d4 = flat & 15;
      float4 g = *(const float4*)&f32v[(jbase + c)*DD + 4*d4];
      *(float4*)&fc_s[c*68 + 4*d4] = g;
    }
    if (t < CT) sqc_s[t] = sqf[jbase + t];
    __syncthreads();
    // distances: 4q x 4c register tile
    float acc[4][4] = {{0.f,0.f,0.f,0.f},{0.f,0.f,0.f,0.f},
                       {0.f,0.f,0.f,0.f},{0.f,0.f,0.f,0.f}};
    #pragma unroll 4
    for (int d4 = 0; d4 < 16; ++d4) {
      float4 a0 = *(const float4*)&fq_s[(q0+0)*68 + 4*d4];
      float4 a1 = *(const float4*)&fq_s[(q0+1)*68 + 4*d4];
      float4 a2 = *(const float4*)&fq_s[(q0+2)*68 + 4*d4];
      float4 a3 = *(const float4*)&fq_s[(q0+3)*68 + 4*d4];
      #pragma unroll
      for (int ic = 0; ic < 4; ++ic) {
        float4 b = *(const float4*)&fc_s[(tc + 32*ic)*68 + 4*d4];
        acc[0][ic] += a0.x*b.x + a0.y*b.y + a0.z*b.z + a0.w*b.w;
        acc[1][ic] += a1.x*b.x + a1.y*b.y + a1.z*b.z + a1.w*b.w;
        acc[2][ic] += a2.x*b.x + a2.y*b.y + a2.z*b.z + a2.w*b.w;
        acc[3][ic] += a3.x*b.x + a3.y*b.y + a3.z*b.z + a3.w*b.w;
      }
    }
    #pragma unroll
    for (int iq = 0; iq < 4; ++iq)
      #pragma unroll
      for (int ic = 0; ic < 4; ++ic)
        dist_s[(q0+iq)*132 + tc + 32*ic] =
            sqq_s[q0+iq] + sqc_s[tc + 32*ic] - 2.0f*acc[iq][ic];
    __syncthreads();
    // selection: wave w owns queries 8w..8w+7
    for (int qq = 0; qq < 8; ++qq) {
      int q = 8*w + qq;
      for (int half = 0; half < 2; ++half) {
        int cl = 64*half + l;
        float dval = dist_s[q*132 + cl];
        float thr = knn_d[q*KSEL + 47];
        unsigned long long mask = __ballot(dval < thr);
        if (!mask) continue;
        float ld = (l < KSEL) ? knn_d[q*KSEL + l] : __builtin_inff();
        int   li = (l < KSEL) ? knn_i[q*KSEL + l] : 0;
        bool wrote = false;
        do {
          int b = __ffsll((unsigned long long)mask) - 1;
          mask &= (mask - 1);
          float dc = __shfl(dval, b);
          if (dc < thr) {                      // wave-uniform
            int jc = jbase + 64*half + b;
            int pos = __popcll(__ballot(l < KSEL && ld <= dc));
            float sd = __shfl_up(ld, 1);
            int   si = __shfl_up(li, 1);
            if (l >= pos) {
              if (l == pos) { ld = dc; li = jc; } else { ld = sd; li = si; }
            }
            thr = __shfl(ld, 47);
            wrote = true;
          }
        } while (mask);
        if (wrote && l < KSEL) { knn_d[q*KSEL + l] = ld; knn_i[q*KSEL + l] = li; }
      }
    }
  }
  __syncthreads();
  for (int qq = 0; qq < 8; ++qq) {
    int q = 8*w + qq;
    if (l < KSEL) idx48[(qbase+q)*KSEL + l] = knn_i[q*KSEL + l];
  }
}

// ---------------- K2b: fp64 exact re-rank of the 48 -> sorted idx40 ----------------
__global__ __launch_bounds__(256) void k2b_rerank(
    const double* __restrict__ f64d, const double* __restrict__ sq64,
    const int* __restrict__ idx48, int* __restrict__ idx40)
{
  __shared__ double sbd[4*KSEL];
  __shared__ int    sbi[4*KSEL];
  const int w = threadIdx.x >> 6, l = threadIdx.x & 63;
  const int node = blockIdx.x*4 + w;
  double dm = 0.0; int cand = 0;
  if (l < KSEL) {
    cand = idx48[node*KSEL + l];
    const double* fi = f64d + node*DD;
    const double* fc = f64d + (long)cand*DD;
    double acc = 0.0;
    #pragma unroll 8
    for (int d = 0; d < DD; ++d) acc += fi[d]*fc[d];
    dm = sq64[node] + sq64[cand] - 2.0*acc;
    sbd[w*KSEL + l] = dm; sbi[w*KSEL + l] = cand;
  }
  __syncthreads();
  if (l < KSEL) {
    int rank = 0;
    for (int j = 0; j < KSEL; ++j) {
      double dj = sbd[w*KSEL + j];
      int    ij = sbi[w*KSEL + j];
      rank += (dj < dm) || (dj == dm && ij < cand);
    }
    if (rank < 40) idx40[node*40 + rank] = cand;
  }
}

// ---------------- K3: two edge-convs + neighbor max-pool ----------------
__global__ __launch_bounds__(256) void k3_edgeconv(
    const float* __restrict__ f32v,
    const float* __restrict__ u1, const float* __restrict__ c1,
    const float* __restrict__ u2, const float* __restrict__ c2,
    const float* __restrict__ Wm1a, const float* __restrict__ bm1a,
    const float* __restrict__ Wm1b, const float* __restrict__ bm1b,
    const float* __restrict__ Wm2a, const float* __restrict__ bm2a,
    const float* __restrict__ Wm2b, const float* __restrict__ bm2b,
    const int* __restrict__ idx40, float* __restrict__ hout)
{
  __shared__ __align__(16) float Wa_s[64*68];
  __shared__ __align__(16) float Wb_s[64*68];
  __shared__ __align__(16) float z_s[20*64];
  __shared__ __align__(16) float a_s[20*64];
  __shared__ float red_s[4*64];
  __shared__ int idx_sh[40];
  const int t = threadIdx.x;
  const int i = blockIdx.x;
  const int w = t >> 6, l = t & 63;
  if (t < 40) idx_sh[t] = idx40[i*40 + t];
  __syncthreads();

  for (int conv = 0; conv < 2; ++conv) {
    const float* Wa_g  = conv ? Wm2a : Wm1a;
    const float* Wbm_g = conv ? Wm2b : Wm1b;
    const float* ba_g  = conv ? bm2a : bm1a;
    const float* bbv_g = conv ? bm2b : bm1b;
    const float* u_g   = conv ? u2 : u1;
    const float* c_g   = conv ? c2 : c1;
    // stage weights (padded rows of 68 for b128 reads)
    #pragma unroll
    for (int r = 0; r < 4; ++r) {
      int flat = t + 256*r;
      int hh = flat >> 4, e4 = flat & 15;
      *(float4*)&Wa_s[hh*68 + 4*e4] = *(const float4*)&Wa_g[hh*64 + 4*e4];
      *(float4*)&Wb_s[hh*68 + 4*e4] = *(const float4*)&Wbm_g[hh*64 + 4*e4];
    }
    // stage z = leaky(c_i - u_nb)
    #pragma unroll
    for (int r = 0; r < 5; ++r) {
      int flat = t + 256*r;
      int k = flat >> 6, d = flat & 63;
      int nb = idx_sh[conv ? 2*k : k];
      float z = c_g[i*DD + d] - u_g[nb*DD + d];
      z_s[k*64 + d] = LEAKY(z);
    }
    __syncthreads();
    // layer A: a[k][h] = leaky(z[k]·Wa[h] + ba[h]); wave w owns k = w,w+4,...,w+16
    float acc[5];
    #pragma unroll
    for (int kk = 0; kk < 5; ++kk) acc[kk] = ba_g[l];
    for (int e4 = 0; e4 < 16; ++e4) {
      float4 wv = *(const float4*)&Wa_s[l*68 + 4*e4];
      #pragma unroll
      for (int kk = 0; kk < 5; ++kk) {
        float4 zv = *(const float4*)&z_s[(w + 4*kk)*64 + 4*e4];
        acc[kk] += zv.x*wv.x + zv.y*wv.y + zv.z*wv.z + zv.w*wv.w;
      }
    }
    #pragma unroll
    for (int kk = 0; kk < 5; ++kk) { float v = acc[kk]; a_s[(w + 4*kk)*64 + l] = LEAKY(v); }
    __syncthreads();
    // layer B + per-wave max over its 5 k's
    float acc2[5];
    #pragma unroll
    for (int kk = 0; kk < 5; ++kk) acc2[kk] = bbv_g[l];
    for (int e4 = 0; e4 < 16; ++e4) {
      float4 wv = *(const float4*)&Wb_s[l*68 + 4*e4];
      #pragma unroll
      for (int kk = 0; kk < 5; ++kk) {
        float4 av = *(const float4*)&a_s[(w + 4*kk)*64 + 4*e4];
        acc2[kk] += av.x*wv.x + av.y*wv.y + av.z*wv.z + av.w*wv.w;
      }
    }
    float m = acc2[0];
    #pragma unroll
    for (int kk = 1; kk < 5; ++kk) m = fmaxf(m, acc2[kk]);
    red_s[w*64 + l] = m;
    __syncthreads();
    if (t < 64) {
      float v = fmaxf(fmaxf(red_s[t], red_s[64+t]), fmaxf(red_s[128+t], red_s[192+t]));
      hout[i*192 + conv*64 + t] = v;
    }
    __syncthreads();
  }
  // h_max over first 9 neighbors of f
  if (t < 64) {
    float m = -__builtin_inff();
    #pragma unroll
    for (int k = 0; k < 9; ++k) m = fmaxf(m, f32v[idx_sh[k]*DD + t]);
    hout[i*192 + 128 + t] = m;
  }
}

// ---------------- K4: final linear + bias + residual ----------------
__global__ __launch_bounds__(256) void k4_final(
    const float* __restrict__ hbuf, const float* __restrict__ WlT,
    const float* __restrict__ bl, const float* __restrict__ feature,
    float* __restrict__ out)
{
  __shared__ __align__(16) float h_sh[16*192];
  const int t = threadIdx.x;
  const int nbase = blockIdx.x * 16;
  #pragma unroll
  for (int r = 0; r < 3; ++r) {
    int flat = t + 256*r;
    int n = flat / 48, j4 = flat % 48;
    *(float4*)&h_sh[n*192 + 4*j4] = *(const float4*)&hbuf[(nbase+n)*192 + 4*j4];
  }
  __syncthreads();
  float acc[16];
  #pragma unroll
  for (int n = 0; n < 16; ++n) acc[n] = 0.f;
  for (int j4 = 0; j4 < 48; ++j4) {
    float w0 = WlT[(4*j4+0)*256 + t];
    float w1 = WlT[(4*j4+1)*256 + t];
    float w2 = WlT[(4*j4+2)*256 + t];
    float w3 = WlT[(4*j4+3)*256 + t];
    #pragma unroll
    for (int n = 0; n < 16; ++n) {
      float4 hv = *(const float4*)&h_sh[n*192 + 4*j4];
      acc[n] += hv.x*w0 + hv.y*w1 + hv.z*w2 + hv.w*w3;
    }
  }
  float blv = bl[t];
  #pragma unroll
  for (int n = 0; n < 16; ++n)
    out[(nbase+n)*256 + t] = acc[n] + blv + feature[(nbase+n)*256 + t];
}

extern "C" void kernel_launch(void* const* d_in, const int* in_sizes, int n_in,
                              void* d_out, int out_size, void* d_ws, size_t ws_size,
                              hipStream_t stream) {
  const float* feature = (const float*)d_in[0];
  const float* Wb   = (const float*)d_in[1];
  const float* bb   = (const float*)d_in[2];
  const float* Wt1  = (const float*)d_in[3];
  const float* bt1  = (const float*)d_in[4];
  const float* Wp1  = (const float*)d_in[5];
  const float* bp1  = (const float*)d_in[6];
  const float* Wm1a = (const float*)d_in[7];
  const float* bm1a = (const float*)d_in[8];
  const float* Wm1b = (const float*)d_in[9];
  const float* bm1b = (const float*)d_in[10];
  const float* Wt2  = (const float*)d_in[11];
  const float* bt2  = (const float*)d_in[12];
  const float* Wp2  = (const float*)d_in[13];
  const float* bp2  = (const float*)d_in[14];
  const float* Wm2a = (const float*)d_in[15];
  const float* bm2a = (const float*)d_in[16];
  const float* Wm2b = (const float*)d_in[17];
  const float* bm2b = (const float*)d_in[18];
  const float* Wl   = (const float*)d_in[19];
  const float* bl   = (const float*)d_in[20];
  float* out = (float*)d_out;

  char* ws = (char*)d_ws;
  double* f64d = (double*)(ws + 0);
  double* sq64 = (double*)(ws + 4194304);
  float*  f32v = (float*)(ws + 4259840);
  float*  sqf  = (float*)(ws + 6356992);
  float*  u1   = (float*)(ws + 6389760);
  float*  c1   = (float*)(ws + 8486912);
  float*  u2   = (float*)(ws + 10584064);
  float*  c2   = (float*)(ws + 12681216);
  int*    idx48= (int*)(ws + 14778368);
  int*    idx40= (int*)(ws + 16351232);
  float*  hbuf = (float*)(ws + 17661952);
  float*  WlT  = (float*)(ws + 23953408);

  hipLaunchKernelGGL(k0_transpose, dim3(192), dim3(256), 0, stream, Wl, WlT);
  hipLaunchKernelGGL(k1_precompute, dim3(2048), dim3(256), 0, stream,
                     feature, Wb, bb, Wt1, bt1, Wp1, bp1, Wt2, bt2, Wp2, bp2,
                     f64d, sq64, f32v, sqf, u1, c1, u2, c2);
  hipLaunchKernelGGL(k2_knn, dim3(NPT/QT), dim3(256), 0, stream, f32v, sqf, idx48);
  hipLaunchKernelGGL(k2b_rerank, dim3(2048), dim3(256), 0, stream, f64d, sq64, idx48, idx40);
  hipLaunchKernelGGL(k3_edgeconv, dim3(8192), dim3(256), 0, stream,
                     f32v, u1, c1, u2, c2, Wm1a, bm1a, Wm1b, bm1b,
                     Wm2a, bm2a, Wm2b, bm2b, idx40, hbuf);
  hipLaunchKernelGGL(k4_final, dim3(512), dim3(256), 0, stream, hbuf, WlT, bl, feature, out);
}

// Round 3
// 721.474 us; speedup vs baseline: 1.6722x; 1.6722x over previous
//
#include <hip/hip_runtime.h>
#include <math.h>

#define NPT   8192
#define FIN   256
#define DD    64
#define KSEL  48

#define LEAKY(x) (((x) >= 0.f) ? (x) : 0.01f*(x))

using short8v = __attribute__((ext_vector_type(8))) short;
using f32x4   = __attribute__((ext_vector_type(4))) float;

__device__ inline unsigned short f2bf(float x) {
  union { float f; unsigned u; } v; v.f = x;
  unsigned r = v.u + 0x7fff + ((v.u >> 16) & 1);   // RNE
  return (unsigned short)(r >> 16);
}
__device__ inline float bf2f(unsigned short h) {
  union { unsigned u; float f; } v; v.u = ((unsigned)h) << 16; return v.f;
}

// ---------------- K0: transposes (Wl, Wb, Wt1, Wp1, Wt2, Wp2) ----------------
__global__ void k0_prep(const float* __restrict__ Wl, const float* __restrict__ Wb,
                        const float* __restrict__ Wt1, const float* __restrict__ Wp1,
                        const float* __restrict__ Wt2, const float* __restrict__ Wp2,
                        float* __restrict__ WlT, float* __restrict__ WbT,
                        float* __restrict__ WtT1, float* __restrict__ WpT1,
                        float* __restrict__ WtT2, float* __restrict__ WpT2)
{
  const int b = blockIdx.x, t = threadIdx.x;
  if (b < 192) {
    WlT[b*256 + t] = Wl[t*192 + b];
  } else if (b < 256) {
    int j = (b - 192)*4 + (t >> 6), o = t & 63;
    WbT[j*64 + o] = Wb[o*256 + j];
  } else {
    int m = b - 256;
    const float* src = (m==0) ? Wt1 : (m==1) ? Wp1 : (m==2) ? Wt2 : Wp2;
    float*       dst = (m==0) ? WtT1: (m==1) ? WpT1: (m==2) ? WtT2: WpT2;
    #pragma unroll
    for (int i = 0; i < 16; ++i) {
      int idx = t + 256*i, r = idx >> 6, c = idx & 63;
      dst[c*64 + r] = src[r*64 + c];
    }
  }
}

// ---------------- K1: per-node precompute ----------------
// f (fp64) = feature@Wb.T + bb ; sq = ||f||^2 ; u = f@Wt.T (fp32); c = f@Wp.T+bp+u+bt (fp32)
__global__ __launch_bounds__(256) void k1_precompute(
    const float* __restrict__ feature, const float* __restrict__ WbT, const float* __restrict__ bb,
    const float* __restrict__ WtT1, const float* __restrict__ bt1,
    const float* __restrict__ WpT1, const float* __restrict__ bp1,
    const float* __restrict__ WtT2, const float* __restrict__ bt2,
    const float* __restrict__ WpT2, const float* __restrict__ bp2,
    double* __restrict__ f64d, double* __restrict__ sq64,
    float* __restrict__ f32v, float* __restrict__ sqf,
    float* __restrict__ u1, float* __restrict__ c1,
    float* __restrict__ u2, float* __restrict__ c2)
{
  __shared__ float f_s[4*64];
  const int w = threadIdx.x >> 6, l = threadIdx.x & 63;
  const int i = blockIdx.x*4 + w;
  const float* frow = feature + i*FIN;
  double facc = (double)bb[l];
  #pragma unroll 4
  for (int j = 0; j < FIN; ++j)
    facc += (double)frow[j] * (double)WbT[j*64 + l];   // coalesced weight read
  f64d[i*DD + l] = facc;
  float f32 = (float)facc;
  f32v[i*DD + l] = f32;
  double s = facc*facc;
  #pragma unroll
  for (int off = 32; off; off >>= 1) s += __shfl_xor(s, off);
  if (l == 0) { sq64[i] = s; sqf[i] = (float)s; }
  f_s[w*64 + l] = f32;
  float au1 = 0.f, ap1 = 0.f, au2 = 0.f, ap2 = 0.f;
  for (int e = 0; e < DD; ++e) {
    float fe = f_s[w*64 + e];          // LDS broadcast
    au1 += fe * WtT1[e*64 + l];
    ap1 += fe * WpT1[e*64 + l];
    au2 += fe * WtT2[e*64 + l];
    ap2 += fe * WpT2[e*64 + l];
  }
  u1[i*DD+l] = au1;
  c1[i*DD+l] = ap1 + bp1[l] + au1 + bt1[l];
  u2[i*DD+l] = au2;
  c2[i*DD+l] = ap2 + bp2[l] + au2 + bt2[l];
}

// ---------------- K1b: build MFMA fragment arrays (bf16 hi/lo split) ----------------
// Sa row layout (K=192): [hi | hi | lo] ; Sb row layout: [hi | lo | hi]
// Fragment (tile,ks): element(row=16*tile+(l&15), k=32*ks+(l>>4)*8+j) at ((tile*6+ks)*64+l)*8+j
__global__ __launch_bounds__(256) void k1b_frag(
    const float* __restrict__ f32v,
    unsigned short* __restrict__ Saf, unsigned short* __restrict__ Sbf)
{
  const int w = threadIdx.x >> 6, l = threadIdx.x & 63;
  const int task = blockIdx.x*4 + w;          // 0..3071
  const int tile = task / 6, ks = task % 6;
  const int row  = tile*16 + (l & 15);
  const int inner = (ks & 1)*32 + ((l >> 4) << 3);
  union { unsigned short u[8]; short8v v; } pa, pb;
  #pragma unroll
  for (int j = 0; j < 8; ++j) {
    float x = f32v[row*64 + inner + j];
    unsigned short hi = f2bf(x);
    unsigned short lo = f2bf(x - bf2f(hi));
    pa.u[j] = (ks < 4) ? hi : lo;
    pb.u[j] = (ks < 2) ? hi : ((ks < 4) ? lo : hi);
  }
  size_t off = ((size_t)(tile*6 + ks)*64 + l)*8;
  *(short8v*)&Saf[off] = pa.v;
  *(short8v*)&Sbf[off] = pb.v;
}

// ---------------- K2: MFMA KNN top-48 ----------------
// 512 thr (8 waves), QT=32 queries/block, grid 256. Wave w: m-tile = w&1, n-pair = w>>1.
// B fragments streamed register-direct from prearranged Sbf (L2-resident), no GEMM LDS.
__global__ __launch_bounds__(512) void k2_knn(
    const unsigned short* __restrict__ Saf,
    const unsigned short* __restrict__ Sbf,
    const float* __restrict__ sqf,
    int* __restrict__ idx48)
{
  __shared__ float sqf_s[NPT];              // 32 KB
  __shared__ float dist_s[32*132];
  __shared__ float knn_d[32*KSEL];
  __shared__ int   knn_i[32*KSEL];

  const int t = threadIdx.x;
  const int w = t >> 6, l = t & 63;
  const int qbase = blockIdx.x * 32;
  const int mt = w & 1, np = w >> 1;

  for (int r = t; r < NPT; r += 512) sqf_s[r] = sqf[r];
  for (int r = t; r < 32*KSEL; r += 512) { knn_d[r] = __builtin_inff(); knn_i[r] = 0; }

  short8v afrag[6];
  {
    const int at = blockIdx.x*2 + mt;
    #pragma unroll
    for (int ks = 0; ks < 6; ++ks)
      afrag[ks] = *(const short8v*)&Saf[((size_t)(at*6 + ks)*64 + l)*8];
  }
  short8v bfrag[2][6];
  #pragma unroll
  for (int nn = 0; nn < 2; ++nn) {
    const int gnt = 2*np + nn;
    #pragma unroll
    for (int ks = 0; ks < 6; ++ks)
      bfrag[nn][ks] = *(const short8v*)&Sbf[((size_t)(gnt*6 + ks)*64 + l)*8];
  }
  __syncthreads();

  for (int cb = 0; cb < NPT/128; ++cb) {
    f32x4 acc[2] = {{0.f,0.f,0.f,0.f},{0.f,0.f,0.f,0.f}};
    #pragma unroll
    for (int nn = 0; nn < 2; ++nn)
      #pragma unroll
      for (int ks = 0; ks < 6; ++ks)
        acc[nn] = __builtin_amdgcn_mfma_f32_16x16x32_bf16(afrag[ks], bfrag[nn][ks], acc[nn], 0, 0, 0);
    if (cb < NPT/128 - 1) {               // prefetch next chunk's B fragments
      #pragma unroll
      for (int nn = 0; nn < 2; ++nn) {
        const int gnt = (cb+1)*8 + 2*np + nn;
        #pragma unroll
        for (int ks = 0; ks < 6; ++ks)
          bfrag[nn][ks] = *(const short8v*)&Sbf[((size_t)(gnt*6 + ks)*64 + l)*8];
      }
    }
    const int jbase = cb*128;
    // C/D layout (m89-verified): row m = (l>>4)*4 + reg, col n = l&15
    #pragma unroll
    for (int nn = 0; nn < 2; ++nn) {
      const int ncol = (2*np + nn)*16 + (l & 15);
      const float sc = sqf_s[jbase + ncol];
      #pragma unroll
      for (int r = 0; r < 4; ++r) {
        const int qrow = mt*16 + ((l >> 4)*4) + r;
        dist_s[qrow*132 + ncol] = sqf_s[qbase + qrow] + sc - 2.0f*acc[nn][r];
      }
    }
    __syncthreads();
    // selection: wave w owns queries 4w..4w+3
    for (int qq = 0; qq < 4; ++qq) {
      const int q = 4*w + qq;
      for (int half = 0; half < 2; ++half) {
        const int cl = 64*half + l;
        float dval = dist_s[q*132 + cl];
        float thr = knn_d[q*KSEL + 47];
        unsigned long long mask = __ballot(dval < thr);
        if (!mask) continue;
        float ld = (l < KSEL) ? knn_d[q*KSEL + l] : __builtin_inff();
        int   li = (l < KSEL) ? knn_i[q*KSEL + l] : 0;
        bool wrote = false;
        do {
          int b = __ffsll((unsigned long long)mask) - 1;
          mask &= (mask - 1);
          float dc = __shfl(dval, b);
          if (dc < thr) {                  // wave-uniform
            int jc = jbase + 64*half + b;
            int pos = __popcll(__ballot(l < KSEL && ld <= dc));
            float sd = __shfl_up(ld, 1);
            int   si = __shfl_up(li, 1);
            if (l >= pos) {
              if (l == pos) { ld = dc; li = jc; } else { ld = sd; li = si; }
            }
            thr = __shfl(ld, 47);
            wrote = true;
          }
        } while (mask);
        if (wrote && l < KSEL) { knn_d[q*KSEL + l] = ld; knn_i[q*KSEL + l] = li; }
      }
    }
    __syncthreads();
  }
  for (int qq = 0; qq < 4; ++qq) {
    const int q = 4*w + qq;
    if (l < KSEL) idx48[(qbase + q)*KSEL + l] = knn_i[q*KSEL + l];
  }
}

// ---------------- K2b: fp64 exact re-rank of the 48 -> sorted idx40 ----------------
__global__ __launch_bounds__(256) void k2b_rerank(
    const double* __restrict__ f64d, const double* __restrict__ sq64,
    const int* __restrict__ idx48, int* __restrict__ idx40)
{
  __shared__ double sbd[4*KSEL];
  __shared__ int    sbi[4*KSEL];
  const int w = threadIdx.x >> 6, l = threadIdx.x & 63;
  const int node = blockIdx.x*4 + w;
  double dm = 0.0; int cand = 0;
  if (l < KSEL) {
    cand = idx48[node*KSEL + l];
    const double* fi = f64d + node*DD;
    const double* fc = f64d + (long)cand*DD;
    double acc = 0.0;
    #pragma unroll 8
    for (int d = 0; d < DD; ++d) acc += fi[d]*fc[d];
    dm = sq64[node] + sq64[cand] - 2.0*acc;
    sbd[w*KSEL + l] = dm; sbi[w*KSEL + l] = cand;
  }
  __syncthreads();
  if (l < KSEL) {
    int rank = 0;
    for (int j = 0; j < KSEL; ++j) {
      double dj = sbd[w*KSEL + j];
      int    ij = sbi[w*KSEL + j];
      rank += (dj < dm) || (dj == dm && ij < cand);
    }
    if (rank < 40) idx40[node*40 + rank] = cand;
  }
}

// ---------------- K3: two edge-convs + neighbor max-pool ----------------
__global__ __launch_bounds__(256) void k3_edgeconv(
    const float* __restrict__ f32v,
    const float* __restrict__ u1, const float* __restrict__ c1,
    const float* __restrict__ u2, const float* __restrict__ c2,
    const float* __restrict__ Wm1a, const float* __restrict__ bm1a,
    const float* __restrict__ Wm1b, const float* __restrict__ bm1b,
    const float* __restrict__ Wm2a, const float* __restrict__ bm2a,
    const float* __restrict__ Wm2b, const float* __restrict__ bm2b,
    const int* __restrict__ idx40, float* __restrict__ hout)
{
  __shared__ __align__(16) float Wa_s[64*68];
  __shared__ __align__(16) float Wb_s[64*68];
  __shared__ __align__(16) float z_s[20*64];
  __shared__ __align__(16) float a_s[20*64];
  __shared__ float red_s[4*64];
  __shared__ int idx_sh[40];
  const int t = threadIdx.x;
  const int i = blockIdx.x;
  const int w = t >> 6, l = t & 63;
  if (t < 40) idx_sh[t] = idx40[i*40 + t];
  __syncthreads();

  for (int conv = 0; conv < 2; ++conv) {
    const float* Wa_g  = conv ? Wm2a : Wm1a;
    const float* Wbm_g = conv ? Wm2b : Wm1b;
    const float* ba_g  = conv ? bm2a : bm1a;
    const float* bbv_g = conv ? bm2b : bm1b;
    const float* u_g   = conv ? u2 : u1;
    const float* c_g   = conv ? c2 : c1;
    #pragma unroll
    for (int r = 0; r < 4; ++r) {
      int flat = t + 256*r;
      int hh = flat >> 4, e4 = flat & 15;
      *(float4*)&Wa_s[hh*68 + 4*e4] = *(const float4*)&Wa_g[hh*64 + 4*e4];
      *(float4*)&Wb_s[hh*68 + 4*e4] = *(const float4*)&Wbm_g[hh*64 + 4*e4];
    }
    #pragma unroll
    for (int r = 0; r < 5; ++r) {
      int flat = t + 256*r;
      int k = flat >> 6, d = flat & 63;
      int nb = idx_sh[conv ? 2*k : k];
      float z = c_g[i*DD + d] - u_g[nb*DD + d];
      z_s[k*64 + d] = LEAKY(z);
    }
    __syncthreads();
    float acc[5];
    #pragma unroll
    for (int kk = 0; kk < 5; ++kk) acc[kk] = ba_g[l];
    for (int e4 = 0; e4 < 16; ++e4) {
      float4 wv = *(const float4*)&Wa_s[l*68 + 4*e4];
      #pragma unroll
      for (int kk = 0; kk < 5; ++kk) {
        float4 zv = *(const float4*)&z_s[(w + 4*kk)*64 + 4*e4];
        acc[kk] += zv.x*wv.x + zv.y*wv.y + zv.z*wv.z + zv.w*wv.w;
      }
    }
    #pragma unroll
    for (int kk = 0; kk < 5; ++kk) { float v = acc[kk]; a_s[(w + 4*kk)*64 + l] = LEAKY(v); }
    __syncthreads();
    float acc2[5];
    #pragma unroll
    for (int kk = 0; kk < 5; ++kk) acc2[kk] = bbv_g[l];
    for (int e4 = 0; e4 < 16; ++e4) {
      float4 wv = *(const float4*)&Wb_s[l*68 + 4*e4];
      #pragma unroll
      for (int kk = 0; kk < 5; ++kk) {
        float4 av = *(const float4*)&a_s[(w + 4*kk)*64 + 4*e4];
        acc2[kk] += av.x*wv.x + av.y*wv.y + av.z*wv.z + av.w*wv.w;
      }
    }
    float m = acc2[0];
    #pragma unroll
    for (int kk = 1; kk < 5; ++kk) m = fmaxf(m, acc2[kk]);
    red_s[w*64 + l] = m;
    __syncthreads();
    if (t < 64) {
      float v = fmaxf(fmaxf(red_s[t], red_s[64+t]), fmaxf(red_s[128+t], red_s[192+t]));
      hout[i*192 + conv*64 + t] = v;
    }
    __syncthreads();
  }
  if (t < 64) {
    float m = -__builtin_inff();
    #pragma unroll
    for (int k = 0; k < 9; ++k) m = fmaxf(m, f32v[idx_sh[k]*DD + t]);
    hout[i*192 + 128 + t] = m;
  }
}

// ---------------- K4: final linear + bias + residual ----------------
__global__ __launch_bounds__(256) void k4_final(
    const float* __restrict__ hbuf, const float* __restrict__ WlT,
    const float* __restrict__ bl, const float* __restrict__ feature,
    float* __restrict__ out)
{
  __shared__ __align__(16) float h_sh[16*192];
  const int t = threadIdx.x;
  const int nbase = blockIdx.x * 16;
  #pragma unroll
  for (int r = 0; r < 3; ++r) {
    int flat = t + 256*r;
    int n = flat / 48, j4 = flat % 48;
    *(float4*)&h_sh[n*192 + 4*j4] = *(const float4*)&hbuf[(nbase+n)*192 + 4*j4];
  }
  __syncthreads();
  float acc[16];
  #pragma unroll
  for (int n = 0; n < 16; ++n) acc[n] = 0.f;
  for (int j4 = 0; j4 < 48; ++j4) {
    float w0 = WlT[(4*j4+0)*256 + t];
    float w1 = WlT[(4*j4+1)*256 + t];
    float w2 = WlT[(4*j4+2)*256 + t];
    float w3 = WlT[(4*j4+3)*256 + t];
    #pragma unroll
    for (int n = 0; n < 16; ++n) {
      float4 hv = *(const float4*)&h_sh[n*192 + 4*j4];
      acc[n] += hv.x*w0 + hv.y*w1 + hv.z*w2 + hv.w*w3;
    }
  }
  float blv = bl[t];
  #pragma unroll
  for (int n = 0; n < 16; ++n)
    out[(nbase+n)*256 + t] = acc[n] + blv + feature[(nbase+n)*256 + t];
}

extern "C" void kernel_launch(void* const* d_in, const int* in_sizes, int n_in,
                              void* d_out, int out_size, void* d_ws, size_t ws_size,
                              hipStream_t stream) {
  const float* feature = (const float*)d_in[0];
  const float* Wb   = (const float*)d_in[1];
  const float* bb   = (const float*)d_in[2];
  const float* Wt1  = (const float*)d_in[3];
  const float* bt1  = (const float*)d_in[4];
  const float* Wp1  = (const float*)d_in[5];
  const float* bp1  = (const float*)d_in[6];
  const float* Wm1a = (const float*)d_in[7];
  const float* bm1a = (const float*)d_in[8];
  const float* Wm1b = (const float*)d_in[9];
  const float* bm1b = (const float*)d_in[10];
  const float* Wt2  = (const float*)d_in[11];
  const float* bt2  = (const float*)d_in[12];
  const float* Wp2  = (const float*)d_in[13];
  const float* bp2  = (const float*)d_in[14];
  const float* Wm2a = (const float*)d_in[15];
  const float* bm2a = (const float*)d_in[16];
  const float* Wm2b = (const float*)d_in[17];
  const float* bm2b = (const float*)d_in[18];
  const float* Wl   = (const float*)d_in[19];
  const float* bl   = (const float*)d_in[20];
  float* out = (float*)d_out;

  char* ws = (char*)d_ws;
  double* f64d = (double*)(ws + 0);
  double* sq64 = (double*)(ws + 4194304);
  float*  f32v = (float*)(ws + 4259840);
  float*  sqf  = (float*)(ws + 6356992);
  float*  u1   = (float*)(ws + 6389760);
  float*  c1   = (float*)(ws + 8486912);
  float*  u2   = (float*)(ws + 10584064);
  float*  c2   = (float*)(ws + 12681216);
  int*    idx48= (int*)(ws + 14778368);
  int*    idx40= (int*)(ws + 16351232);
  float*  hbuf = (float*)(ws + 17661952);
  float*  WlT  = (float*)(ws + 23953408);
  unsigned short* Saf = (unsigned short*)(ws + 24150016);
  unsigned short* Sbf = (unsigned short*)(ws + 27295744);
  float*  WbT  = (float*)(ws + 30441472);
  float*  WtT1 = (float*)(ws + 30507008);
  float*  WpT1 = (float*)(ws + 30523392);
  float*  WtT2 = (float*)(ws + 30539776);
  float*  WpT2 = (float*)(ws + 30556160);

  hipLaunchKernelGGL(k0_prep, dim3(260), dim3(256), 0, stream,
                     Wl, Wb, Wt1, Wp1, Wt2, Wp2, WlT, WbT, WtT1, WpT1, WtT2, WpT2);
  hipLaunchKernelGGL(k1_precompute, dim3(2048), dim3(256), 0, stream,
                     feature, WbT, bb, WtT1, bt1, WpT1, bp1, WtT2, bt2, WpT2, bp2,
                     f64d, sq64, f32v, sqf, u1, c1, u2, c2);
  hipLaunchKernelGGL(k1b_frag, dim3(768), dim3(256), 0, stream, f32v, Saf, Sbf);
  hipLaunchKernelGGL(k2_knn, dim3(NPT/32), dim3(512), 0, stream, Saf, Sbf, sqf, idx48);
  hipLaunchKernelGGL(k2b_rerank, dim3(2048), dim3(256), 0, stream, f64d, sq64, idx48, idx40);
  hipLaunchKernelGGL(k3_edgeconv, dim3(8192), dim3(256), 0, stream,
                     f32v, u1, c1, u2, c2, Wm1a, bm1a, Wm1b, bm1b,
                     Wm2a, bm2a, Wm2b, bm2b, idx40, hbuf);
  hipLaunchKernelGGL(k4_final, dim3(512), dim3(256), 0, stream, hbuf, WlT, bl, feature, out);
}

// Round 4
// 549.024 us; speedup vs baseline: 2.1974x; 1.3141x over previous
//
#include <hip/hip_runtime.h>
#include <math.h>

#define NPT   8192
#define FIN   256
#define DD    64
#define KSEL  48
#define QT    16

#define LEAKY(x) (((x) >= 0.f) ? (x) : 0.01f*(x))

using short8v = __attribute__((ext_vector_type(8))) short;
using f32x4   = __attribute__((ext_vector_type(4))) float;

__device__ inline unsigned short f2bf(float x) {
  union { float f; unsigned u; } v; v.f = x;
  unsigned r = v.u + 0x7fff + ((v.u >> 16) & 1);   // RNE
  return (unsigned short)(r >> 16);
}
__device__ inline float bf2f(unsigned short h) {
  union { unsigned u; float f; } v; v.u = ((unsigned)h) << 16; return v.f;
}

// Sort (sd,si) ascending across 64 lanes (bitonic, 21 stages), then merge with
// sorted list (ld,li): keep lowest-64 of the union, re-sorted ascending.
__device__ __forceinline__ void sort_merge(float& ld, int& li, float sd, int si, int l) {
  #pragma unroll
  for (int k = 2; k <= 64; k <<= 1) {
    #pragma unroll
    for (int j = k >> 1; j >= 1; j >>= 1) {
      float pd = __shfl_xor(sd, j);
      int   pi = __shfl_xor(si, j);
      bool up = ((l & k) == 0);          // l&64==0 always -> final pass ascending
      bool lower = ((l & j) == 0);
      bool takeMin = (up == lower);
      bool pick = takeMin ? (pd < sd) : (pd > sd);
      sd = pick ? pd : sd;
      si = pick ? pi : si;
    }
  }
  // merge: reverse buffer, elementwise min -> bitonic lowest-64, then 6 clean stages
  float rd = __shfl(sd, 63 - l);
  int   ri = __shfl(si, 63 - l);
  bool keep = (ld <= rd);
  float md = keep ? ld : rd;
  int   mi = keep ? li : ri;
  #pragma unroll
  for (int j = 32; j >= 1; j >>= 1) {
    float pd = __shfl_xor(md, j);
    int   pi = __shfl_xor(mi, j);
    bool lower = ((l & j) == 0);
    bool pick = lower ? (pd < md) : (pd > md);
    md = pick ? pd : md;
    mi = pick ? pi : mi;
  }
  ld = md; li = mi;
}

// ---------------- K0: transposes (Wl, Wb, Wt1, Wp1, Wt2, Wp2) ----------------
__global__ void k0_prep(const float* __restrict__ Wl, const float* __restrict__ Wb,
                        const float* __restrict__ Wt1, const float* __restrict__ Wp1,
                        const float* __restrict__ Wt2, const float* __restrict__ Wp2,
                        float* __restrict__ WlT, float* __restrict__ WbT,
                        float* __restrict__ WtT1, float* __restrict__ WpT1,
                        float* __restrict__ WtT2, float* __restrict__ WpT2)
{
  const int b = blockIdx.x, t = threadIdx.x;
  if (b < 192) {
    WlT[b*256 + t] = Wl[t*192 + b];
  } else if (b < 256) {
    int j = (b - 192)*4 + (t >> 6), o = t & 63;
    WbT[j*64 + o] = Wb[o*256 + j];
  } else {
    int m = b - 256;
    const float* src = (m==0) ? Wt1 : (m==1) ? Wp1 : (m==2) ? Wt2 : Wp2;
    float*       dst = (m==0) ? WtT1: (m==1) ? WpT1: (m==2) ? WtT2: WpT2;
    #pragma unroll
    for (int i = 0; i < 16; ++i) {
      int idx = t + 256*i, r = idx >> 6, c = idx & 63;
      dst[c*64 + r] = src[r*64 + c];
    }
  }
}

// ---------------- K1: per-node precompute ----------------
__global__ __launch_bounds__(256) void k1_precompute(
    const float* __restrict__ feature, const float* __restrict__ WbT, const float* __restrict__ bb,
    const float* __restrict__ WtT1, const float* __restrict__ bt1,
    const float* __restrict__ WpT1, const float* __restrict__ bp1,
    const float* __restrict__ WtT2, const float* __restrict__ bt2,
    const float* __restrict__ WpT2, const float* __restrict__ bp2,
    double* __restrict__ f64d, double* __restrict__ sq64,
    float* __restrict__ f32v, float* __restrict__ sqf,
    float* __restrict__ u1, float* __restrict__ c1,
    float* __restrict__ u2, float* __restrict__ c2)
{
  __shared__ float f_s[4*64];
  const int w = threadIdx.x >> 6, l = threadIdx.x & 63;
  const int i = blockIdx.x*4 + w;
  const float* frow = feature + i*FIN;
  double facc = (double)bb[l];
  #pragma unroll 4
  for (int j = 0; j < FIN; ++j)
    facc += (double)frow[j] * (double)WbT[j*64 + l];
  f64d[i*DD + l] = facc;
  float f32 = (float)facc;
  f32v[i*DD + l] = f32;
  double s = facc*facc;
  #pragma unroll
  for (int off = 32; off; off >>= 1) s += __shfl_xor(s, off);
  if (l == 0) { sq64[i] = s; sqf[i] = (float)s; }
  f_s[w*64 + l] = f32;
  float au1 = 0.f, ap1 = 0.f, au2 = 0.f, ap2 = 0.f;
  for (int e = 0; e < DD; ++e) {
    float fe = f_s[w*64 + e];
    au1 += fe * WtT1[e*64 + l];
    ap1 += fe * WpT1[e*64 + l];
    au2 += fe * WtT2[e*64 + l];
    ap2 += fe * WpT2[e*64 + l];
  }
  u1[i*DD+l] = au1;
  c1[i*DD+l] = ap1 + bp1[l] + au1 + bt1[l];
  u2[i*DD+l] = au2;
  c2[i*DD+l] = ap2 + bp2[l] + au2 + bt2[l];
}

// ---------------- K1b: build MFMA fragment arrays (bf16 hi/lo split) ----------------
__global__ __launch_bounds__(256) void k1b_frag(
    const float* __restrict__ f32v,
    unsigned short* __restrict__ Saf, unsigned short* __restrict__ Sbf)
{
  const int w = threadIdx.x >> 6, l = threadIdx.x & 63;
  const int task = blockIdx.x*4 + w;          // 0..3071
  const int tile = task / 6, ks = task % 6;
  const int row  = tile*16 + (l & 15);
  const int inner = (ks & 1)*32 + ((l >> 4) << 3);
  union { unsigned short u[8]; short8v v; } pa, pb;
  #pragma unroll
  for (int j = 0; j < 8; ++j) {
    float x = f32v[row*64 + inner + j];
    unsigned short hi = f2bf(x);
    unsigned short lo = f2bf(x - bf2f(hi));
    pa.u[j] = (ks < 4) ? hi : lo;
    pb.u[j] = (ks < 2) ? hi : ((ks < 4) ? lo : hi);
  }
  size_t off = ((size_t)(tile*6 + ks)*64 + l)*8;
  *(short8v*)&Saf[off] = pa.v;
  *(short8v*)&Sbf[off] = pb.v;
}

// ---------------- K2: MFMA KNN top-48, batched bitonic selection ----------------
// 512 thr (8 waves), QT=16 queries/block, grid 512 (2 blocks/CU).
// Wave w computes n-tile w of each 128-cand chunk; owns queries 2w, 2w+1.
__global__ __launch_bounds__(512) void k2_knn(
    const unsigned short* __restrict__ Saf,
    const unsigned short* __restrict__ Sbf,
    const float* __restrict__ sqf,
    int* __restrict__ idx48)
{
  __shared__ float sqf_s[NPT];              // 32 KB
  __shared__ float dist_s[QT*132];          // 8.4 KB
  __shared__ float buf_d[8*2*64];           // 4 KB wave-private buffers
  __shared__ int   buf_i[8*2*64];           // 4 KB

  const int t = threadIdx.x;
  const int w = t >> 6, l = t & 63;
  const int qbase = blockIdx.x * QT;

  for (int r = t; r < NPT; r += 512) sqf_s[r] = sqf[r];

  short8v afrag[6];
  #pragma unroll
  for (int ks = 0; ks < 6; ++ks)
    afrag[ks] = *(const short8v*)&Saf[((size_t)(blockIdx.x*6 + ks)*64 + l)*8];
  short8v bfrag[6];
  #pragma unroll
  for (int ks = 0; ks < 6; ++ks)
    bfrag[ks] = *(const short8v*)&Sbf[((size_t)(w*6 + ks)*64 + l)*8];

  // per-query selection state (2 queries per wave)
  float ld[2] = {__builtin_inff(), __builtin_inff()};
  int   li[2] = {0, 0};
  float thr[2] = {__builtin_inff(), __builtin_inff()};
  int   bc[2] = {0, 0};

  __syncthreads();

  for (int cb = 0; cb < NPT/128; ++cb) {
    const int jbase = cb*128;
    f32x4 acc = {0.f, 0.f, 0.f, 0.f};
    #pragma unroll
    for (int ks = 0; ks < 6; ++ks)
      acc = __builtin_amdgcn_mfma_f32_16x16x32_bf16(afrag[ks], bfrag[ks], acc, 0, 0, 0);
    if (cb < NPT/128 - 1) {                  // prefetch next chunk's B fragments
      const int gnt = (cb+1)*8 + w;
      #pragma unroll
      for (int ks = 0; ks < 6; ++ks)
        bfrag[ks] = *(const short8v*)&Sbf[((size_t)(gnt*6 + ks)*64 + l)*8];
    }
    // C/D layout: row m = (l>>4)*4 + reg, col n = l&15
    {
      const int ncol = w*16 + (l & 15);
      const float sc = sqf_s[jbase + ncol];
      #pragma unroll
      for (int r = 0; r < 4; ++r) {
        const int qrow = ((l >> 4)*4) + r;
        dist_s[qrow*132 + ncol] = sqf_s[qbase + qrow] + sc - 2.0f*acc[r];
      }
    }
    __syncthreads();
    // selection: wave w owns queries 2w, 2w+1
    #pragma unroll
    for (int qq = 0; qq < 2; ++qq) {
      const int q = 2*w + qq;
      float* bufd = &buf_d[(w*2 + qq)*64];
      int*   bufi = &buf_i[(w*2 + qq)*64];
      #pragma unroll
      for (int half = 0; half < 2; ++half) {
        float d = dist_s[q*132 + 64*half + l];
        bool pass = d < thr[qq];
        unsigned long long m = __ballot(pass);
        if (m) {
          int cnt = __popcll(m);
          int bco = bc[qq];
          if (bco + cnt > 64) {               // flush buffer into list
            float sd = (l < bco) ? bufd[l] : __builtin_inff();
            int   si = (l < bco) ? bufi[l] : 0;
            sort_merge(ld[qq], li[qq], sd, si, l);
            thr[qq] = __shfl(ld[qq], 47);
            bco = 0;
          }
          if (pass) {
            int slot = bco + __popcll(m & ((1ull << l) - 1ull));
            bufd[slot] = d;
            bufi[slot] = jbase + 64*half + l;
          }
          bc[qq] = bco + cnt;
        }
      }
    }
    __syncthreads();
  }
  // final flush + output
  #pragma unroll
  for (int qq = 0; qq < 2; ++qq) {
    const int q = 2*w + qq;
    if (bc[qq] > 0) {
      float* bufd = &buf_d[(w*2 + qq)*64];
      int*   bufi = &buf_i[(w*2 + qq)*64];
      float sd = (l < bc[qq]) ? bufd[l] : __builtin_inff();
      int   si = (l < bc[qq]) ? bufi[l] : 0;
      sort_merge(ld[qq], li[qq], sd, si, l);
    }
    if (l < KSEL) idx48[(qbase + q)*KSEL + l] = li[qq];
  }
}

// ---------------- K2b: fp64 exact re-rank of the 48 -> sorted idx40 ----------------
__global__ __launch_bounds__(256) void k2b_rerank(
    const double* __restrict__ f64d, const double* __restrict__ sq64,
    const int* __restrict__ idx48, int* __restrict__ idx40)
{
  __shared__ double sbd[4*KSEL];
  __shared__ int    sbi[4*KSEL];
  const int w = threadIdx.x >> 6, l = threadIdx.x & 63;
  const int node = blockIdx.x*4 + w;
  double dm = 0.0; int cand = 0;
  if (l < KSEL) {
    cand = idx48[node*KSEL + l];
    const double* fi = f64d + node*DD;
    const double* fc = f64d + (long)cand*DD;
    double acc = 0.0;
    #pragma unroll 8
    for (int d = 0; d < DD; ++d) acc += fi[d]*fc[d];
    dm = sq64[node] + sq64[cand] - 2.0*acc;
    sbd[w*KSEL + l] = dm; sbi[w*KSEL + l] = cand;
  }
  __syncthreads();
  if (l < KSEL) {
    int rank = 0;
    for (int j = 0; j < KSEL; ++j) {
      double dj = sbd[w*KSEL + j];
      int    ij = sbi[w*KSEL + j];
      rank += (dj < dm) || (dj == dm && ij < cand);
    }
    if (rank < 40) idx40[node*40 + rank] = cand;
  }
}

// ---------------- K3: two edge-convs + neighbor max-pool ----------------
__global__ __launch_bounds__(256) void k3_edgeconv(
    const float* __restrict__ f32v,
    const float* __restrict__ u1, const float* __restrict__ c1,
    const float* __restrict__ u2, const float* __restrict__ c2,
    const float* __restrict__ Wm1a, const float* __restrict__ bm1a,
    const float* __restrict__ Wm1b, const float* __restrict__ bm1b,
    const float* __restrict__ Wm2a, const float* __restrict__ bm2a,
    const float* __restrict__ Wm2b, const float* __restrict__ bm2b,
    const int* __restrict__ idx40, float* __restrict__ hout)
{
  __shared__ __align__(16) float Wa_s[64*68];
  __shared__ __align__(16) float Wb_s[64*68];
  __shared__ __align__(16) float z_s[20*64];
  __shared__ __align__(16) float a_s[20*64];
  __shared__ float red_s[4*64];
  __shared__ int idx_sh[40];
  const int t = threadIdx.x;
  const int i = blockIdx.x;
  const int w = t >> 6, l = t & 63;
  if (t < 40) idx_sh[t] = idx40[i*40 + t];
  __syncthreads();

  for (int conv = 0; conv < 2; ++conv) {
    const float* Wa_g  = conv ? Wm2a : Wm1a;
    const float* Wbm_g = conv ? Wm2b : Wm1b;
    const float* ba_g  = conv ? bm2a : bm1a;
    const float* bbv_g = conv ? bm2b : bm1b;
    const float* u_g   = conv ? u2 : u1;
    const float* c_g   = conv ? c2 : c1;
    #pragma unroll
    for (int r = 0; r < 4; ++r) {
      int flat = t + 256*r;
      int hh = flat >> 4, e4 = flat & 15;
      *(float4*)&Wa_s[hh*68 + 4*e4] = *(const float4*)&Wa_g[hh*64 + 4*e4];
      *(float4*)&Wb_s[hh*68 + 4*e4] = *(const float4*)&Wbm_g[hh*64 + 4*e4];
    }
    #pragma unroll
    for (int r = 0; r < 5; ++r) {
      int flat = t + 256*r;
      int k = flat >> 6, d = flat & 63;
      int nb = idx_sh[conv ? 2*k : k];
      float z = c_g[i*DD + d] - u_g[nb*DD + d];
      z_s[k*64 + d] = LEAKY(z);
    }
    __syncthreads();
    float acc[5];
    #pragma unroll
    for (int kk = 0; kk < 5; ++kk) acc[kk] = ba_g[l];
    for (int e4 = 0; e4 < 16; ++e4) {
      float4 wv = *(const float4*)&Wa_s[l*68 + 4*e4];
      #pragma unroll
      for (int kk = 0; kk < 5; ++kk) {
        float4 zv = *(const float4*)&z_s[(w + 4*kk)*64 + 4*e4];
        acc[kk] += zv.x*wv.x + zv.y*wv.y + zv.z*wv.z + zv.w*wv.w;
      }
    }
    #pragma unroll
    for (int kk = 0; kk < 5; ++kk) { float v = acc[kk]; a_s[(w + 4*kk)*64 + l] = LEAKY(v); }
    __syncthreads();
    float acc2[5];
    #pragma unroll
    for (int kk = 0; kk < 5; ++kk) acc2[kk] = bbv_g[l];
    for (int e4 = 0; e4 < 16; ++e4) {
      float4 wv = *(const float4*)&Wb_s[l*68 + 4*e4];
      #pragma unroll
      for (int kk = 0; kk < 5; ++kk) {
        float4 av = *(const float4*)&a_s[(w + 4*kk)*64 + 4*e4];
        acc2[kk] += av.x*wv.x + av.y*wv.y + av.z*wv.z + av.w*wv.w;
      }
    }
    float m = acc2[0];
    #pragma unroll
    for (int kk = 1; kk < 5; ++kk) m = fmaxf(m, acc2[kk]);
    red_s[w*64 + l] = m;
    __syncthreads();
    if (t < 64) {
      float v = fmaxf(fmaxf(red_s[t], red_s[64+t]), fmaxf(red_s[128+t], red_s[192+t]));
      hout[i*192 + conv*64 + t] = v;
    }
    __syncthreads();
  }
  if (t < 64) {
    float m = -__builtin_inff();
    #pragma unroll
    for (int k = 0; k < 9; ++k) m = fmaxf(m, f32v[idx_sh[k]*DD + t]);
    hout[i*192 + 128 + t] = m;
  }
}

// ---------------- K4: final linear + bias + residual ----------------
__global__ __launch_bounds__(256) void k4_final(
    const float* __restrict__ hbuf, const float* __restrict__ WlT,
    const float* __restrict__ bl, const float* __restrict__ feature,
    float* __restrict__ out)
{
  __shared__ __align__(16) float h_sh[16*192];
  const int t = threadIdx.x;
  const int nbase = blockIdx.x * 16;
  #pragma unroll
  for (int r = 0; r < 3; ++r) {
    int flat = t + 256*r;
    int n = flat / 48, j4 = flat % 48;
    *(float4*)&h_sh[n*192 + 4*j4] = *(const float4*)&hbuf[(nbase+n)*192 + 4*j4];
  }
  __syncthreads();
  float acc[16];
  #pragma unroll
  for (int n = 0; n < 16; ++n) acc[n] = 0.f;
  for (int j4 = 0; j4 < 48; ++j4) {
    float w0 = WlT[(4*j4+0)*256 + t];
    float w1 = WlT[(4*j4+1)*256 + t];
    float w2 = WlT[(4*j4+2)*256 + t];
    float w3 = WlT[(4*j4+3)*256 + t];
    #pragma unroll
    for (int n = 0; n < 16; ++n) {
      float4 hv = *(const float4*)&h_sh[n*192 + 4*j4];
      acc[n] += hv.x*w0 + hv.y*w1 + hv.z*w2 + hv.w*w3;
    }
  }
  float blv = bl[t];
  #pragma unroll
  for (int n = 0; n < 16; ++n)
    out[(nbase+n)*256 + t] = acc[n] + blv + feature[(nbase+n)*256 + t];
}

extern "C" void kernel_launch(void* const* d_in, const int* in_sizes, int n_in,
                              void* d_out, int out_size, void* d_ws, size_t ws_size,
                              hipStream_t stream) {
  const float* feature = (const float*)d_in[0];
  const float* Wb   = (const float*)d_in[1];
  const float* bb   = (const float*)d_in[2];
  const float* Wt1  = (const float*)d_in[3];
  const float* bt1  = (const float*)d_in[4];
  const float* Wp1  = (const float*)d_in[5];
  const float* bp1  = (const float*)d_in[6];
  const float* Wm1a = (const float*)d_in[7];
  const float* bm1a = (const float*)d_in[8];
  const float* Wm1b = (const float*)d_in[9];
  const float* bm1b = (const float*)d_in[10];
  const float* Wt2  = (const float*)d_in[11];
  const float* bt2  = (const float*)d_in[12];
  const float* Wp2  = (const float*)d_in[13];
  const float* bp2  = (const float*)d_in[14];
  const float* Wm2a = (const float*)d_in[15];
  const float* bm2a = (const float*)d_in[16];
  const float* Wm2b = (const float*)d_in[17];
  const float* bm2b = (const float*)d_in[18];
  const float* Wl   = (const float*)d_in[19];
  const float* bl   = (const float*)d_in[20];
  float* out = (float*)d_out;

  char* ws = (char*)d_ws;
  double* f64d = (double*)(ws + 0);
  double* sq64 = (double*)(ws + 4194304);
  float*  f32v = (float*)(ws + 4259840);
  float*  sqf  = (float*)(ws + 6356992);
  float*  u1   = (float*)(ws + 6389760);
  float*  c1   = (float*)(ws + 8486912);
  float*  u2   = (float*)(ws + 10584064);
  float*  c2   = (float*)(ws + 12681216);
  int*    idx48= (int*)(ws + 14778368);
  int*    idx40= (int*)(ws + 16351232);
  float*  hbuf = (float*)(ws + 17661952);
  float*  WlT  = (float*)(ws + 23953408);
  unsigned short* Saf = (unsigned short*)(ws + 24150016);
  unsigned short* Sbf = (unsigned short*)(ws + 27295744);
  float*  WbT  = (float*)(ws + 30441472);
  float*  WtT1 = (float*)(ws + 30507008);
  float*  WpT1 = (float*)(ws + 30523392);
  float*  WtT2 = (float*)(ws + 30539776);
  float*  WpT2 = (float*)(ws + 30556160);

  hipLaunchKernelGGL(k0_prep, dim3(260), dim3(256), 0, stream,
                     Wl, Wb, Wt1, Wp1, Wt2, Wp2, WlT, WbT, WtT1, WpT1, WtT2, WpT2);
  hipLaunchKernelGGL(k1_precompute, dim3(2048), dim3(256), 0, stream,
                     feature, WbT, bb, WtT1, bt1, WpT1, bp1, WtT2, bt2, WpT2, bp2,
                     f64d, sq64, f32v, sqf, u1, c1, u2, c2);
  hipLaunchKernelGGL(k1b_frag, dim3(768), dim3(256), 0, stream, f32v, Saf, Sbf);
  hipLaunchKernelGGL(k2_knn, dim3(NPT/QT), dim3(512), 0, stream, Saf, Sbf, sqf, idx48);
  hipLaunchKernelGGL(k2b_rerank, dim3(2048), dim3(256), 0, stream, f64d, sq64, idx48, idx40);
  hipLaunchKernelGGL(k3_edgeconv, dim3(8192), dim3(256), 0, stream,
                     f32v, u1, c1, u2, c2, Wm1a, bm1a, Wm1b, bm1b,
                     Wm2a, bm2a, Wm2b, bm2b, idx40, hbuf);
  hipLaunchKernelGGL(k4_final, dim3(512), dim3(256), 0, stream, hbuf, WlT, bl, feature, out);
}

// Round 5
// 437.795 us; speedup vs baseline: 2.7557x; 1.2541x over previous
//
#include <hip/hip_runtime.h>
#include <math.h>

#define NPT   8192
#define FIN   256
#define DD    64
#define KSEL  48
#define QT    16

#define LEAKY(x) (((x) >= 0.f) ? (x) : 0.01f*(x))

using short8v = __attribute__((ext_vector_type(8))) short;
using f32x4   = __attribute__((ext_vector_type(4))) float;

__device__ inline unsigned short f2bf(float x) {
  union { float f; unsigned u; } v; v.f = x;
  unsigned r = v.u + 0x7fff + ((v.u >> 16) & 1);   // RNE
  return (unsigned short)(r >> 16);
}
__device__ inline float bf2f(unsigned short h) {
  union { unsigned u; float f; } v; v.u = ((unsigned)h) << 16; return v.f;
}

// Sort (sd,si) ascending across 64 lanes (bitonic), then merge with sorted
// (ld,li): keep lowest-64 of the union, re-sorted ascending.
__device__ __forceinline__ void sort_merge(float& ld, int& li, float sd, int si, int l) {
  #pragma unroll
  for (int k = 2; k <= 64; k <<= 1) {
    #pragma unroll
    for (int j = k >> 1; j >= 1; j >>= 1) {
      float pd = __shfl_xor(sd, j);
      int   pi = __shfl_xor(si, j);
      bool up = ((l & k) == 0);
      bool lower = ((l & j) == 0);
      bool takeMin = (up == lower);
      bool pick = takeMin ? (pd < sd) : (pd > sd);
      sd = pick ? pd : sd;
      si = pick ? pi : si;
    }
  }
  float rd = __shfl(sd, 63 - l);
  int   ri = __shfl(si, 63 - l);
  bool keep = (ld <= rd);
  float md = keep ? ld : rd;
  int   mi = keep ? li : ri;
  #pragma unroll
  for (int j = 32; j >= 1; j >>= 1) {
    float pd = __shfl_xor(md, j);
    int   pi = __shfl_xor(mi, j);
    bool lower = ((l & j) == 0);
    bool pick = lower ? (pd < md) : (pd > md);
    md = pick ? pd : md;
    mi = pick ? pi : mi;
  }
  ld = md; li = mi;
}

// ---------------- K0: transposes ----------------
__global__ void k0_prep(const float* __restrict__ Wl, const float* __restrict__ Wb,
                        const float* __restrict__ Wt1, const float* __restrict__ Wp1,
                        const float* __restrict__ Wt2, const float* __restrict__ Wp2,
                        float* __restrict__ WlT, float* __restrict__ WbT,
                        float* __restrict__ WtT1, float* __restrict__ WpT1,
                        float* __restrict__ WtT2, float* __restrict__ WpT2)
{
  const int b = blockIdx.x, t = threadIdx.x;
  if (b < 192) {
    WlT[b*256 + t] = Wl[t*192 + b];
  } else if (b < 256) {
    int j = (b - 192)*4 + (t >> 6), o = t & 63;
    WbT[j*64 + o] = Wb[o*256 + j];
  } else {
    int m = b - 256;
    const float* src = (m==0) ? Wt1 : (m==1) ? Wp1 : (m==2) ? Wt2 : Wp2;
    float*       dst = (m==0) ? WtT1: (m==1) ? WpT1: (m==2) ? WtT2: WpT2;
    #pragma unroll
    for (int i = 0; i < 16; ++i) {
      int idx = t + 256*i, r = idx >> 6, c = idx & 63;
      dst[c*64 + r] = src[r*64 + c];
    }
  }
}

// ---------------- K1: per-node precompute ----------------
__global__ __launch_bounds__(256) void k1_precompute(
    const float* __restrict__ feature, const float* __restrict__ WbT, const float* __restrict__ bb,
    const float* __restrict__ WtT1, const float* __restrict__ bt1,
    const float* __restrict__ WpT1, const float* __restrict__ bp1,
    const float* __restrict__ WtT2, const float* __restrict__ bt2,
    const float* __restrict__ WpT2, const float* __restrict__ bp2,
    double* __restrict__ f64d, double* __restrict__ sq64,
    float* __restrict__ f32v, float* __restrict__ sqf,
    float* __restrict__ u1, float* __restrict__ c1,
    float* __restrict__ u2, float* __restrict__ c2)
{
  __shared__ float f_s[4*64];
  const int w = threadIdx.x >> 6, l = threadIdx.x & 63;
  const int i = blockIdx.x*4 + w;
  const float* frow = feature + i*FIN;
  double facc = (double)bb[l];
  #pragma unroll 4
  for (int j = 0; j < FIN; ++j)
    facc += (double)frow[j] * (double)WbT[j*64 + l];
  f64d[i*DD + l] = facc;
  float f32 = (float)facc;
  f32v[i*DD + l] = f32;
  double s = facc*facc;
  #pragma unroll
  for (int off = 32; off; off >>= 1) s += __shfl_xor(s, off);
  if (l == 0) { sq64[i] = s; sqf[i] = (float)s; }
  f_s[w*64 + l] = f32;
  float au1 = 0.f, ap1 = 0.f, au2 = 0.f, ap2 = 0.f;
  for (int e = 0; e < DD; ++e) {
    float fe = f_s[w*64 + e];
    au1 += fe * WtT1[e*64 + l];
    ap1 += fe * WpT1[e*64 + l];
    au2 += fe * WtT2[e*64 + l];
    ap2 += fe * WpT2[e*64 + l];
  }
  u1[i*DD+l] = au1;
  c1[i*DD+l] = ap1 + bp1[l] + au1 + bt1[l];
  u2[i*DD+l] = au2;
  c2[i*DD+l] = ap2 + bp2[l] + au2 + bt2[l];
}

// ---------------- K1b: MFMA fragments for KNN (bf16 hi/lo) ----------------
// slot ks layout: A=[hi(x0),hi(x1),hi(x0),hi(x1),lo(x0),lo(x1)], B=[hi,hi,lo,lo,hi,hi per (x0,x1)]
__global__ __launch_bounds__(256) void k1b_frag(
    const float* __restrict__ f32v,
    unsigned short* __restrict__ Saf, unsigned short* __restrict__ Sbf)
{
  const int w = threadIdx.x >> 6, l = threadIdx.x & 63;
  const int task = blockIdx.x*4 + w;          // 0..3071
  const int tile = task / 6, ks = task % 6;
  const int row  = tile*16 + (l & 15);
  const int inner = (ks & 1)*32 + ((l >> 4) << 3);
  union { unsigned short u[8]; short8v v; } pa, pb;
  #pragma unroll
  for (int j = 0; j < 8; ++j) {
    float x = f32v[row*64 + inner + j];
    unsigned short hi = f2bf(x);
    unsigned short lo = f2bf(x - bf2f(hi));
    pa.u[j] = (ks < 4) ? hi : lo;
    pb.u[j] = (ks < 2) ? hi : ((ks < 4) ? lo : hi);
  }
  size_t off = ((size_t)(tile*6 + ks)*64 + l)*8;
  *(short8v*)&Saf[off] = pa.v;
  *(short8v*)&Sbf[off] = pb.v;
}

// ---------------- K1c: weight B-fragments for edge-conv MLPs ----------------
__global__ __launch_bounds__(256) void k1c_wfrag(
    const float* __restrict__ Wm1a, const float* __restrict__ Wm1b,
    const float* __restrict__ Wm2a, const float* __restrict__ Wm2b,
    unsigned short* __restrict__ F1a, unsigned short* __restrict__ F1b,
    unsigned short* __restrict__ F2a, unsigned short* __restrict__ F2b)
{
  const int w = threadIdx.x >> 6, l = threadIdx.x & 63;
  const int task = blockIdx.x*4 + w;          // 0..95
  const int which = task / 24, rem = task % 24;
  const int nt = rem / 6, ks = rem % 6;
  const float* W = (which==0) ? Wm1a : (which==1) ? Wm1b : (which==2) ? Wm2a : Wm2b;
  unsigned short* F = (which==0) ? F1a : (which==1) ? F1b : (which==2) ? F2a : F2b;
  const int row = nt*16 + (l & 15);
  const int inner = (ks & 1)*32 + ((l >> 4) << 3);
  union { unsigned short u[8]; short8v v; } p;
  #pragma unroll
  for (int j = 0; j < 8; ++j) {
    float x = W[row*64 + inner + j];
    unsigned short hi = f2bf(x);
    unsigned short lo = f2bf(x - bf2f(hi));
    p.u[j] = (ks < 2) ? hi : ((ks < 4) ? lo : hi);
  }
  *(short8v*)&F[((size_t)(nt*6 + ks)*64 + l)*8] = p.v;
}

// ---------------- K2: MFMA KNN top-48, batched bitonic selection ----------------
// 512 thr (8 waves), QT=16 queries/block, grid 512.
// d' = sq_cand - 2*dot (query-sq constant dropped: order-preserving).
__global__ __launch_bounds__(512) void k2_knn(
    const unsigned short* __restrict__ Saf,
    const unsigned short* __restrict__ Sbf,
    const float* __restrict__ sqf,
    int* __restrict__ idx48)
{
  __shared__ float dist_s[2][QT*132];       // 16.9 KB double-buffered
  __shared__ float buf_d[8*2*64];           // 4 KB
  __shared__ int   buf_i[8*2*64];           // 4 KB

  const int t = threadIdx.x;
  const int w = t >> 6, l = t & 63;
  const int qbase = blockIdx.x * QT;

  short8v afr[4];                            // hi0,hi1,lo0,lo1
  {
    const size_t b = (size_t)blockIdx.x*6;
    afr[0] = *(const short8v*)&Saf[((b+0)*64 + l)*8];
    afr[1] = *(const short8v*)&Saf[((b+1)*64 + l)*8];
    afr[2] = *(const short8v*)&Saf[((b+4)*64 + l)*8];
    afr[3] = *(const short8v*)&Saf[((b+5)*64 + l)*8];
  }
  short8v bfr[4];                            // hi0,hi1,lo0,lo1
  {
    const size_t b = (size_t)w*6;
    #pragma unroll
    for (int s = 0; s < 4; ++s)
      bfr[s] = *(const short8v*)&Sbf[((b+s)*64 + l)*8];
  }

  float ld[2] = {__builtin_inff(), __builtin_inff()};
  int   li[2] = {0, 0};
  float thr[2] = {__builtin_inff(), __builtin_inff()};
  int   bc[2] = {0, 0};

  for (int cb = 0; cb < NPT/128; ++cb) {
    const int jbase = cb*128;
    const float sc = sqf[jbase + w*16 + (l & 15)];
    f32x4 acc = {0.f, 0.f, 0.f, 0.f};
    acc = __builtin_amdgcn_mfma_f32_16x16x32_bf16(afr[0], bfr[0], acc, 0, 0, 0);
    acc = __builtin_amdgcn_mfma_f32_16x16x32_bf16(afr[1], bfr[1], acc, 0, 0, 0);
    acc = __builtin_amdgcn_mfma_f32_16x16x32_bf16(afr[0], bfr[2], acc, 0, 0, 0);
    acc = __builtin_amdgcn_mfma_f32_16x16x32_bf16(afr[1], bfr[3], acc, 0, 0, 0);
    acc = __builtin_amdgcn_mfma_f32_16x16x32_bf16(afr[2], bfr[0], acc, 0, 0, 0);
    acc = __builtin_amdgcn_mfma_f32_16x16x32_bf16(afr[3], bfr[1], acc, 0, 0, 0);
    if (cb < NPT/128 - 1) {
      const size_t b = (size_t)((cb+1)*8 + w)*6;
      #pragma unroll
      for (int s = 0; s < 4; ++s)
        bfr[s] = *(const short8v*)&Sbf[((b+s)*64 + l)*8];
    }
    {
      const int ncol = w*16 + (l & 15);
      #pragma unroll
      for (int r = 0; r < 4; ++r) {
        const int qrow = ((l >> 4)*4) + r;
        dist_s[cb&1][qrow*132 + ncol] = sc - 2.0f*acc[r];
      }
    }
    __syncthreads();
    #pragma unroll
    for (int qq = 0; qq < 2; ++qq) {
      const int q = 2*w + qq;
      float* bufd = &buf_d[(w*2 + qq)*64];
      int*   bufi = &buf_i[(w*2 + qq)*64];
      #pragma unroll
      for (int half = 0; half < 2; ++half) {
        float d = dist_s[cb&1][q*132 + 64*half + l];
        bool pass = d < thr[qq];
        unsigned long long m = __ballot(pass);
        if (m) {
          int cnt = __popcll(m);
          int bco = bc[qq];
          if (bco + cnt > 64) {
            float sd = (l < bco) ? bufd[l] : __builtin_inff();
            int   si = (l < bco) ? bufi[l] : 0;
            sort_merge(ld[qq], li[qq], sd, si, l);
            thr[qq] = __shfl(ld[qq], 47);
            bco = 0;
          }
          if (pass) {
            int slot = bco + __popcll(m & ((1ull << l) - 1ull));
            bufd[slot] = d;
            bufi[slot] = jbase + 64*half + l;
          }
          bc[qq] = bco + cnt;
        }
      }
    }
  }
  #pragma unroll
  for (int qq = 0; qq < 2; ++qq) {
    const int q = 2*w + qq;
    if (bc[qq] > 0) {
      float* bufd = &buf_d[(w*2 + qq)*64];
      int*   bufi = &buf_i[(w*2 + qq)*64];
      float sd = (l < bc[qq]) ? bufd[l] : __builtin_inff();
      int   si = (l < bc[qq]) ? bufi[l] : 0;
      sort_merge(ld[qq], li[qq], sd, si, l);
    }
    if (l < KSEL) idx48[(qbase + q)*KSEL + l] = li[qq];
  }
}

// ---------------- K2b: fp64 exact re-rank of the 48 -> sorted idx40 ----------------
__global__ __launch_bounds__(256) void k2b_rerank(
    const double* __restrict__ f64d, const double* __restrict__ sq64,
    const int* __restrict__ idx48, int* __restrict__ idx40)
{
  __shared__ double sbd[4*KSEL];
  __shared__ int    sbi[4*KSEL];
  const int w = threadIdx.x >> 6, l = threadIdx.x & 63;
  const int node = blockIdx.x*4 + w;
  double dm = 0.0; int cand = 0;
  if (l < KSEL) {
    cand = idx48[node*KSEL + l];
    const double* fi = f64d + node*DD;
    const double* fc = f64d + (long)cand*DD;
    double acc = 0.0;
    #pragma unroll 8
    for (int d = 0; d < DD; ++d) acc += fi[d]*fc[d];
    dm = sq64[node] + sq64[cand] - 2.0*acc;
    sbd[w*KSEL + l] = dm; sbi[w*KSEL + l] = cand;
  }
  __syncthreads();
  if (l < KSEL) {
    int rank = 0;
    for (int j = 0; j < KSEL; ++j) {
      double dj = sbd[w*KSEL + j];
      int    ij = sbi[w*KSEL + j];
      rank += (dj < dm) || (dj == dm && ij < cand);
    }
    if (rank < 40) idx40[node*40 + rank] = cand;
  }
}

// Build A-operand hi/lo fragments from a 32x64 fp32 tile in LDS (stride 68).
__device__ __forceinline__ void build_frags(const float* __restrict__ zs, int mt, int l,
                                            short8v fr[4]) {
  const int row = mt*16 + (l & 15);
  const int base = row*68 + ((l >> 4) << 3);
  union { unsigned short u[8]; short8v v; } h0, h1, q0, q1;
  #pragma unroll
  for (int j = 0; j < 8; ++j) {
    float x0 = zs[base + j];
    float x1 = zs[base + 32 + j];
    unsigned short a = f2bf(x0);
    unsigned short b = f2bf(x1);
    h0.u[j] = a; q0.u[j] = f2bf(x0 - bf2f(a));
    h1.u[j] = b; q1.u[j] = f2bf(x1 - bf2f(b));
  }
  fr[0] = h0.v; fr[1] = h1.v; fr[2] = q0.v; fr[3] = q1.v;
}

#define MFMA6(ACC, AF, W0, W1, W2, W3)                                          \
  ACC = __builtin_amdgcn_mfma_f32_16x16x32_bf16(AF[0], W0, ACC, 0, 0, 0);       \
  ACC = __builtin_amdgcn_mfma_f32_16x16x32_bf16(AF[1], W1, ACC, 0, 0, 0);       \
  ACC = __builtin_amdgcn_mfma_f32_16x16x32_bf16(AF[0], W2, ACC, 0, 0, 0);       \
  ACC = __builtin_amdgcn_mfma_f32_16x16x32_bf16(AF[1], W3, ACC, 0, 0, 0);       \
  ACC = __builtin_amdgcn_mfma_f32_16x16x32_bf16(AF[2], W0, ACC, 0, 0, 0);       \
  ACC = __builtin_amdgcn_mfma_f32_16x16x32_bf16(AF[3], W1, ACC, 0, 0, 0);

// ---------------- K3: MFMA edge-convs + neighbor max-pool ----------------
// Block per node. 4 waves: wave w -> m-tile (w>>1), n-tiles {2*(w&1), 2*(w&1)+1}.
__global__ __launch_bounds__(256) void k3_edgeconv(
    const float* __restrict__ f32v,
    const float* __restrict__ u1, const float* __restrict__ c1,
    const float* __restrict__ u2, const float* __restrict__ c2,
    const unsigned short* __restrict__ F1a, const unsigned short* __restrict__ F1b,
    const unsigned short* __restrict__ F2a, const unsigned short* __restrict__ F2b,
    const float* __restrict__ bm1a, const float* __restrict__ bm1b,
    const float* __restrict__ bm2a, const float* __restrict__ bm2b,
    const int* __restrict__ idx40, float* __restrict__ hout)
{
  __shared__ __align__(16) float z_s[32*68];
  __shared__ __align__(16) float a_s[32*68];
  __shared__ float red_s[2*64];
  __shared__ int idx_sh[40];
  const int t = threadIdx.x, i = blockIdx.x;
  const int w = t >> 6, l = t & 63;
  const int mt = w >> 1;
  const int nb0 = (w & 1)*2;
  if (t < 40) idx_sh[t] = idx40[i*40 + t];
  __syncthreads();

  for (int conv = 0; conv < 2; ++conv) {
    const float* u_g = conv ? u2 : u1;
    const float* c_g = conv ? c2 : c1;
    const unsigned short* WfA = conv ? F2a : F1a;
    const unsigned short* WfB = conv ? F2b : F1b;
    const float* bav = conv ? bm2a : bm1a;
    const float* bbv = conv ? bm2b : bm1b;
    // stage z (32x64 padded rows zero, stride 68)
    #pragma unroll
    for (int r = 0; r < 8; ++r) {
      int flat = t + 256*r, row = flat >> 6, d = flat & 63;
      float z = 0.f;
      if (row < 20) {
        int nb = idx_sh[conv ? 2*row : row];
        float zv = c_g[i*DD + d] - u_g[nb*DD + d];
        z = LEAKY(zv);
      }
      z_s[row*68 + d] = z;
    }
    __syncthreads();
    // === layer A ===
    short8v afr[4];
    build_frags(z_s, mt, l, afr);
    f32x4 acc0 = {0.f,0.f,0.f,0.f}, acc1 = {0.f,0.f,0.f,0.f};
    {
      const unsigned short* p0 = WfA + ((size_t)(nb0+0)*6*64)*8;
      const unsigned short* p1 = WfA + ((size_t)(nb0+1)*6*64)*8;
      short8v w00 = *(const short8v*)&p0[(0*64+l)*8];
      short8v w01 = *(const short8v*)&p0[(1*64+l)*8];
      short8v w02 = *(const short8v*)&p0[(2*64+l)*8];
      short8v w03 = *(const short8v*)&p0[(3*64+l)*8];
      short8v w10 = *(const short8v*)&p1[(0*64+l)*8];
      short8v w11 = *(const short8v*)&p1[(1*64+l)*8];
      short8v w12 = *(const short8v*)&p1[(2*64+l)*8];
      short8v w13 = *(const short8v*)&p1[(3*64+l)*8];
      MFMA6(acc0, afr, w00, w01, w02, w03);
      MFMA6(acc1, afr, w10, w11, w12, w13);
    }
    {
      const int c0 = (nb0+0)*16 + (l & 15), c1i = (nb0+1)*16 + (l & 15);
      const float ba0 = bav[c0], ba1 = bav[c1i];
      #pragma unroll
      for (int r = 0; r < 4; ++r) {
        const int row = mt*16 + (l >> 4)*4 + r;
        float v0 = acc0[r] + ba0;
        float v1 = acc1[r] + ba1;
        a_s[row*68 + c0]  = LEAKY(v0);
        a_s[row*68 + c1i] = LEAKY(v1);
      }
    }
    __syncthreads();
    // === layer B + masked max ===
    short8v bfr[4];
    build_frags(a_s, mt, l, bfr);
    f32x4 bacc0 = {0.f,0.f,0.f,0.f}, bacc1 = {0.f,0.f,0.f,0.f};
    {
      const unsigned short* p0 = WfB + ((size_t)(nb0+0)*6*64)*8;
      const unsigned short* p1 = WfB + ((size_t)(nb0+1)*6*64)*8;
      short8v w00 = *(const short8v*)&p0[(0*64+l)*8];
      short8v w01 = *(const short8v*)&p0[(1*64+l)*8];
      short8v w02 = *(const short8v*)&p0[(2*64+l)*8];
      short8v w03 = *(const short8v*)&p0[(3*64+l)*8];
      short8v w10 = *(const short8v*)&p1[(0*64+l)*8];
      short8v w11 = *(const short8v*)&p1[(1*64+l)*8];
      short8v w12 = *(const short8v*)&p1[(2*64+l)*8];
      short8v w13 = *(const short8v*)&p1[(3*64+l)*8];
      MFMA6(bacc0, bfr, w00, w01, w02, w03);
      MFMA6(bacc1, bfr, w10, w11, w12, w13);
    }
    {
      const int c0 = (nb0+0)*16 + (l & 15), c1i = (nb0+1)*16 + (l & 15);
      const float bb0 = bbv[c0], bb1 = bbv[c1i];
      float m0 = -__builtin_inff(), m1 = -__builtin_inff();
      #pragma unroll
      for (int r = 0; r < 4; ++r) {
        const int row = mt*16 + (l >> 4)*4 + r;
        if (row < 20) {
          m0 = fmaxf(m0, bacc0[r] + bb0);
          m1 = fmaxf(m1, bacc1[r] + bb1);
        }
      }
      m0 = fmaxf(m0, __shfl_xor(m0, 16)); m0 = fmaxf(m0, __shfl_xor(m0, 32));
      m1 = fmaxf(m1, __shfl_xor(m1, 16)); m1 = fmaxf(m1, __shfl_xor(m1, 32));
      if ((l >> 4) == 0) {
        red_s[mt*64 + c0]  = m0;
        red_s[mt*64 + c1i] = m1;
      }
    }
    __syncthreads();
    if (t < 64) hout[i*192 + conv*64 + t] = fmaxf(red_s[t], red_s[64 + t]);
    __syncthreads();
  }
  if (t < 64) {
    float m = -__builtin_inff();
    #pragma unroll
    for (int k = 0; k < 9; ++k) m = fmaxf(m, f32v[idx_sh[k]*DD + t]);
    hout[i*192 + 128 + t] = m;
  }
}

// ---------------- K4: final linear + bias + residual ----------------
__global__ __launch_bounds__(256) void k4_final(
    const float* __restrict__ hbuf, const float* __restrict__ WlT,
    const float* __restrict__ bl, const float* __restrict__ feature,
    float* __restrict__ out)
{
  __shared__ __align__(16) float h_sh[16*192];
  const int t = threadIdx.x;
  const int nbase = blockIdx.x * 16;
  #pragma unroll
  for (int r = 0; r < 3; ++r) {
    int flat = t + 256*r;
    int n = flat / 48, j4 = flat % 48;
    *(float4*)&h_sh[n*192 + 4*j4] = *(const float4*)&hbuf[(nbase+n)*192 + 4*j4];
  }
  __syncthreads();
  float acc[16];
  #pragma unroll
  for (int n = 0; n < 16; ++n) acc[n] = 0.f;
  for (int j4 = 0; j4 < 48; ++j4) {
    float w0 = WlT[(4*j4+0)*256 + t];
    float w1 = WlT[(4*j4+1)*256 + t];
    float w2 = WlT[(4*j4+2)*256 + t];
    float w3 = WlT[(4*j4+3)*256 + t];
    #pragma unroll
    for (int n = 0; n < 16; ++n) {
      float4 hv = *(const float4*)&h_sh[n*192 + 4*j4];
      acc[n] += hv.x*w0 + hv.y*w1 + hv.z*w2 + hv.w*w3;
    }
  }
  float blv = bl[t];
  #pragma unroll
  for (int n = 0; n < 16; ++n)
    out[(nbase+n)*256 + t] = acc[n] + blv + feature[(nbase+n)*256 + t];
}

extern "C" void kernel_launch(void* const* d_in, const int* in_sizes, int n_in,
                              void* d_out, int out_size, void* d_ws, size_t ws_size,
                              hipStream_t stream) {
  const float* feature = (const float*)d_in[0];
  const float* Wb   = (const float*)d_in[1];
  const float* bb   = (const float*)d_in[2];
  const float* Wt1  = (const float*)d_in[3];
  const float* bt1  = (const float*)d_in[4];
  const float* Wp1  = (const float*)d_in[5];
  const float* bp1  = (const float*)d_in[6];
  const float* Wm1a = (const float*)d_in[7];
  const float* bm1a = (const float*)d_in[8];
  const float* Wm1b = (const float*)d_in[9];
  const float* bm1b = (const float*)d_in[10];
  const float* Wt2  = (const float*)d_in[11];
  const float* bt2  = (const float*)d_in[12];
  const float* Wp2  = (const float*)d_in[13];
  const float* bp2  = (const float*)d_in[14];
  const float* Wm2a = (const float*)d_in[15];
  const float* bm2a = (const float*)d_in[16];
  const float* Wm2b = (const float*)d_in[17];
  const float* bm2b = (const float*)d_in[18];
  const float* Wl   = (const float*)d_in[19];
  const float* bl   = (const float*)d_in[20];
  float* out = (float*)d_out;

  char* ws = (char*)d_ws;
  double* f64d = (double*)(ws + 0);
  double* sq64 = (double*)(ws + 4194304);
  float*  f32v = (float*)(ws + 4259840);
  float*  sqf  = (float*)(ws + 6356992);
  float*  u1   = (float*)(ws + 6389760);
  float*  c1   = (float*)(ws + 8486912);
  float*  u2   = (float*)(ws + 10584064);
  float*  c2   = (float*)(ws + 12681216);
  int*    idx48= (int*)(ws + 14778368);
  int*    idx40= (int*)(ws + 16351232);
  float*  hbuf = (float*)(ws + 17661952);
  float*  WlT  = (float*)(ws + 23953408);
  unsigned short* Saf = (unsigned short*)(ws + 24150016);
  unsigned short* Sbf = (unsigned short*)(ws + 27295744);
  float*  WbT  = (float*)(ws + 30441472);
  float*  WtT1 = (float*)(ws + 30507008);
  float*  WpT1 = (float*)(ws + 30523392);
  float*  WtT2 = (float*)(ws + 30539776);
  float*  WpT2 = (float*)(ws + 30556160);
  unsigned short* F1a = (unsigned short*)(ws + 30572544);
  unsigned short* F1b = (unsigned short*)(ws + 30597120);
  unsigned short* F2a = (unsigned short*)(ws + 30621696);
  unsigned short* F2b = (unsigned short*)(ws + 30646272);

  hipLaunchKernelGGL(k0_prep, dim3(260), dim3(256), 0, stream,
                     Wl, Wb, Wt1, Wp1, Wt2, Wp2, WlT, WbT, WtT1, WpT1, WtT2, WpT2);
  hipLaunchKernelGGL(k1c_wfrag, dim3(24), dim3(256), 0, stream,
                     Wm1a, Wm1b, Wm2a, Wm2b, F1a, F1b, F2a, F2b);
  hipLaunchKernelGGL(k1_precompute, dim3(2048), dim3(256), 0, stream,
                     feature, WbT, bb, WtT1, bt1, WpT1, bp1, WtT2, bt2, WpT2, bp2,
                     f64d, sq64, f32v, sqf, u1, c1, u2, c2);
  hipLaunchKernelGGL(k1b_frag, dim3(768), dim3(256), 0, stream, f32v, Saf, Sbf);
  hipLaunchKernelGGL(k2_knn, dim3(NPT/QT), dim3(512), 0, stream, Saf, Sbf, sqf, idx48);
  hipLaunchKernelGGL(k2b_rerank, dim3(2048), dim3(256), 0, stream, f64d, sq64, idx48, idx40);
  hipLaunchKernelGGL(k3_edgeconv, dim3(8192), dim3(256), 0, stream,
                     f32v, u1, c1, u2, c2, F1a, F1b, F2a, F2b,
                     bm1a, bm1b, bm2a, bm2b, idx40, hbuf);
  hipLaunchKernelGGL(k4_final, dim3(512), dim3(256), 0, stream, hbuf, WlT, bl, feature, out);
}